// Round 1
// baseline (898.339 us; speedup 1.0000x reference)
//
#include <hip/hip_runtime.h>
#include <stdint.h>
#include <math.h>

#define TOKENS 8192
#define DMODEL 2048
#define HID    8192
#define BK     64

typedef __attribute__((ext_vector_type(4))) int v4i;

// ---------------- weight absmean: partial |w| sums (fp64) ----------------
__global__ __launch_bounds__(256) void k_abssum(const float* __restrict__ w, long long n4,
                                                double* __restrict__ partial) {
  long long i0 = (long long)blockIdx.x * 256 + threadIdx.x;
  long long stride = (long long)gridDim.x * 256;
  const float4* w4 = (const float4*)w;
  double s = 0.0;
  for (long long i = i0; i < n4; i += stride) {
    float4 v = w4[i];
    s += (double)fabsf(v.x) + (double)fabsf(v.y) + (double)fabsf(v.z) + (double)fabsf(v.w);
  }
  __shared__ double sm[256];
  sm[threadIdx.x] = s;
  __syncthreads();
  for (int off = 128; off > 0; off >>= 1) {
    if ((int)threadIdx.x < off) sm[threadIdx.x] += sm[threadIdx.x + off];
    __syncthreads();
  }
  if (threadIdx.x == 0) partial[blockIdx.x] = sm[0];
}

// ---------------- finalize: s = max(mean|w|, 1e-5) for both weights ----------------
__global__ __launch_bounds__(256) void k_finalize(const double* __restrict__ pg, int ng, double cg,
                                                  const double* __restrict__ po, int no, double co,
                                                  float* __restrict__ scales) {
  __shared__ double sm[256];
  int tid = threadIdx.x;
  double s = 0.0;
  for (int i = tid; i < ng; i += 256) s += pg[i];
  sm[tid] = s; __syncthreads();
  for (int off = 128; off > 0; off >>= 1) { if (tid < off) sm[tid] += sm[tid + off]; __syncthreads(); }
  if (tid == 0) scales[0] = (float)fmax(sm[0] / cg, 1e-5);
  __syncthreads();
  s = 0.0;
  for (int i = tid; i < no; i += 256) s += po[i];
  sm[tid] = s; __syncthreads();
  for (int off = 128; off > 0; off >>= 1) { if (tid < off) sm[tid] += sm[tid + off]; __syncthreads(); }
  if (tid == 0) scales[1] = (float)fmax(sm[0] / co, 1e-5);
}

// ---------------- ternary weight quant: q = clip(rint(w/s), -1, 1) ----------------
__global__ __launch_bounds__(256) void k_wquant(const float* __restrict__ w, long long n4,
                                                const float* __restrict__ sptr,
                                                uint8_t* __restrict__ q) {
  long long i = (long long)blockIdx.x * 256 + threadIdx.x;
  if (i >= n4) return;
  float s = *sptr;
  float4 v = ((const float4*)w)[i];
  int q0 = (int)rintf(v.x / s); q0 = q0 < -1 ? -1 : (q0 > 1 ? 1 : q0);
  int q1 = (int)rintf(v.y / s); q1 = q1 < -1 ? -1 : (q1 > 1 ? 1 : q1);
  int q2 = (int)rintf(v.z / s); q2 = q2 < -1 ? -1 : (q2 > 1 ? 1 : q2);
  int q3 = (int)rintf(v.w / s); q3 = q3 < -1 ? -1 : (q3 > 1 ? 1 : q3);
  uint32_t packed = (uint32_t)(q0 & 0xff) | ((uint32_t)(q1 & 0xff) << 8) |
                    ((uint32_t)(q2 & 0xff) << 16) | ((uint32_t)(q3 & 0xff) << 24);
  ((uint32_t*)q)[i] = packed;
}

__device__ __forceinline__ int q127(float a) {
  float r = rintf(a);
  r = fminf(fmaxf(r, -127.0f), 127.0f);
  return (int)r;
}

// ---------------- fused RMSNorm + per-token int8 quant ----------------
__global__ __launch_bounds__(256) void k_rmsnorm_quant(const float* __restrict__ x,
                                                       const float* __restrict__ g,
                                                       uint8_t* __restrict__ a1,
                                                       float* __restrict__ d1) {
  int t = blockIdx.x;
  int tid = threadIdx.x;
  const float4* xr = (const float4*)(x + (long long)t * DMODEL);
  const float4* gr = (const float4*)g;
  float4 xv[2], gv[2];
  xv[0] = xr[tid]; xv[1] = xr[tid + 256];
  gv[0] = gr[tid]; gv[1] = gr[tid + 256];
  double ss = 0.0;
  for (int p = 0; p < 2; p++) {
    float4 v = xv[p];
    ss += (double)v.x * v.x + (double)v.y * v.y + (double)v.z * v.z + (double)v.w * v.w;
  }
  int lane = tid & 63, wave = tid >> 6;
  for (int off = 32; off > 0; off >>= 1) ss += __shfl_down(ss, off);
  __shared__ double wsum[4];
  if (lane == 0) wsum[wave] = ss;
  __syncthreads();
  double var = (wsum[0] + wsum[1] + wsum[2] + wsum[3]) / (double)DMODEL;
  float r = (float)(1.0 / sqrt(var + 1e-5));
  float h[8];
  h[0] = xv[0].x * r * gv[0].x; h[1] = xv[0].y * r * gv[0].y;
  h[2] = xv[0].z * r * gv[0].z; h[3] = xv[0].w * r * gv[0].w;
  h[4] = xv[1].x * r * gv[1].x; h[5] = xv[1].y * r * gv[1].y;
  h[6] = xv[1].z * r * gv[1].z; h[7] = xv[1].w * r * gv[1].w;
  float am = 0.f;
  for (int k = 0; k < 8; k++) am = fmaxf(am, fabsf(h[k]));
  for (int off = 32; off > 0; off >>= 1) am = fmaxf(am, __shfl_down(am, off));
  __shared__ float wmax[4];
  if (lane == 0) wmax[wave] = am;
  __syncthreads();
  float amc = fmaxf(fmaxf(fmaxf(wmax[0], wmax[1]), fmaxf(wmax[2], wmax[3])), 1e-5f);
  float scale = 127.0f / amc;
  uint32_t* arow = (uint32_t*)(a1 + (long long)t * DMODEL);
  for (int p = 0; p < 2; p++) {
    int q0 = q127(h[p * 4 + 0] * scale);
    int q1 = q127(h[p * 4 + 1] * scale);
    int q2 = q127(h[p * 4 + 2] * scale);
    int q3 = q127(h[p * 4 + 3] * scale);
    arow[tid + p * 256] = (uint32_t)(q0 & 0xff) | ((uint32_t)(q1 & 0xff) << 8) |
                          ((uint32_t)(q2 & 0xff) << 16) | ((uint32_t)(q3 & 0xff) << 24);
  }
  if (tid == 0) d1[t] = amc / 127.0f;
}

// ---------------- GEMM1 (int8 MFMA) + fused SwiGLU ----------------
// A [8192][2048] i8, Bq [16384][2048] i8 ternary (row-major = B^T pattern).
// Block: 128 tokens x 128 channels of the 8192-half; computes value & gate, writes h2 fp32.
__global__ __launch_bounds__(256, 2) void k_gemm1_swiglu(
    const uint8_t* __restrict__ A, const uint8_t* __restrict__ Bq,
    const float* __restrict__ d1, const float* __restrict__ scales,
    float* __restrict__ H2) {
  __shared__ __align__(16) uint8_t sA[128 * BK];
  __shared__ __align__(16) uint8_t sBv[128 * BK];
  __shared__ __align__(16) uint8_t sBg[128 * BK];
  int tid = threadIdx.x;
  int lane = tid & 63, wave = tid >> 6;
  int wm = (wave >> 1) * 64, wn = (wave & 1) * 64;
  long long m0 = (long long)blockIdx.y * 128;
  long long n0 = (long long)blockIdx.x * 128;
  const uint8_t* Ab = A + m0 * DMODEL;
  const uint8_t* Bv = Bq + n0 * DMODEL;
  const uint8_t* Bg = Bq + (n0 + (long long)HID) * DMODEL;
  int sr = tid >> 2;
  int sc = (tid & 3) << 4;
  v4i accv[4][4] = {};
  v4i accg[4][4] = {};
  for (int k0 = 0; k0 < DMODEL; k0 += BK) {
    __syncthreads();
    *(int4*)(sA + sr * BK + sc)        = *(const int4*)(Ab + (long long)sr * DMODEL + k0 + sc);
    *(int4*)(sA + (sr + 64) * BK + sc) = *(const int4*)(Ab + (long long)(sr + 64) * DMODEL + k0 + sc);
    *(int4*)(sBv + sr * BK + sc)        = *(const int4*)(Bv + (long long)sr * DMODEL + k0 + sc);
    *(int4*)(sBv + (sr + 64) * BK + sc) = *(const int4*)(Bv + (long long)(sr + 64) * DMODEL + k0 + sc);
    *(int4*)(sBg + sr * BK + sc)        = *(const int4*)(Bg + (long long)sr * DMODEL + k0 + sc);
    *(int4*)(sBg + (sr + 64) * BK + sc) = *(const int4*)(Bg + (long long)(sr + 64) * DMODEL + k0 + sc);
    __syncthreads();
    int rsel = lane & 15;
    int ksel = (lane >> 4) << 4;
    v4i af[4], bfv[4], bfg[4];
    for (int i = 0; i < 4; i++) af[i] = *(const v4i*)(sA + (wm + i * 16 + rsel) * BK + ksel);
    for (int j = 0; j < 4; j++) bfv[j] = *(const v4i*)(sBv + (wn + j * 16 + rsel) * BK + ksel);
    for (int j = 0; j < 4; j++) bfg[j] = *(const v4i*)(sBg + (wn + j * 16 + rsel) * BK + ksel);
    for (int i = 0; i < 4; i++)
      for (int j = 0; j < 4; j++) {
        accv[i][j] = __builtin_amdgcn_mfma_i32_16x16x64_i8(af[i], bfv[j], accv[i][j], 0, 0, 0);
        accg[i][j] = __builtin_amdgcn_mfma_i32_16x16x64_i8(af[i], bfg[j], accg[i][j], 0, 0, 0);
      }
  }
  float sgv = scales[0];
  int rowb = (int)m0 + wm + ((lane >> 4) << 2);
  int colb = (int)n0 + wn + (lane & 15);
  for (int i = 0; i < 4; i++) {
    for (int r = 0; r < 4; r++) {
      int token = rowb + i * 16 + r;
      float ds = d1[token] * sgv;
      float* hrow = H2 + (long long)token * HID;
      for (int j = 0; j < 4; j++) {
        float v = (float)accv[i][j][r] * ds;
        float gg = (float)accg[i][j][r] * ds;
        float sil = gg / (1.0f + expf(-gg));  // silu(gate)
        hrow[colb + j * 16] = v * sil;
      }
    }
  }
}

// ---------------- per-token int8 quant of h2 (row of 8192) ----------------
__global__ __launch_bounds__(256) void k_hquant(const float* __restrict__ H2,
                                                uint8_t* __restrict__ A2,
                                                float* __restrict__ d2) {
  int t = blockIdx.x;
  int tid = threadIdx.x;
  const float4* hr = (const float4*)(H2 + (long long)t * HID);
  float4 v[8];
  float am = 0.f;
  for (int p = 0; p < 8; p++) {
    v[p] = hr[tid + p * 256];
    am = fmaxf(am, fmaxf(fmaxf(fabsf(v[p].x), fabsf(v[p].y)), fmaxf(fabsf(v[p].z), fabsf(v[p].w))));
  }
  int lane = tid & 63, wave = tid >> 6;
  for (int off = 32; off > 0; off >>= 1) am = fmaxf(am, __shfl_down(am, off));
  __shared__ float wmax[4];
  if (lane == 0) wmax[wave] = am;
  __syncthreads();
  float amc = fmaxf(fmaxf(fmaxf(wmax[0], wmax[1]), fmaxf(wmax[2], wmax[3])), 1e-5f);
  float scale = 127.0f / amc;
  uint32_t* arow = (uint32_t*)(A2 + (long long)t * HID);
  for (int p = 0; p < 8; p++) {
    int q0 = q127(v[p].x * scale);
    int q1 = q127(v[p].y * scale);
    int q2 = q127(v[p].z * scale);
    int q3 = q127(v[p].w * scale);
    arow[tid + p * 256] = (uint32_t)(q0 & 0xff) | ((uint32_t)(q1 & 0xff) << 8) |
                          ((uint32_t)(q2 & 0xff) << 16) | ((uint32_t)(q3 & 0xff) << 24);
  }
  if (tid == 0) d2[t] = amc / 127.0f;
}

// ---------------- GEMM2 (int8 MFMA) + residual add ----------------
// A2 [8192][8192] i8, Bq [2048][8192] i8 ternary, out = x + A2*Bq^T * (d2 ⊗ s_out)
__global__ __launch_bounds__(256, 2) void k_gemm2_resid(
    const uint8_t* __restrict__ A2, const uint8_t* __restrict__ Bq,
    const float* __restrict__ d2, const float* __restrict__ scales,
    const float* __restrict__ x, float* __restrict__ out) {
  __shared__ __align__(16) uint8_t sA[128 * BK];
  __shared__ __align__(16) uint8_t sB[128 * BK];
  int tid = threadIdx.x;
  int lane = tid & 63, wave = tid >> 6;
  int wm = (wave >> 1) * 64, wn = (wave & 1) * 64;
  long long m0 = (long long)blockIdx.y * 128;
  long long n0 = (long long)blockIdx.x * 128;
  const uint8_t* Ab = A2 + m0 * HID;
  const uint8_t* Bb = Bq + n0 * HID;
  int sr = tid >> 2;
  int sc = (tid & 3) << 4;
  v4i acc[4][4] = {};
  for (int k0 = 0; k0 < HID; k0 += BK) {
    __syncthreads();
    *(int4*)(sA + sr * BK + sc)        = *(const int4*)(Ab + (long long)sr * HID + k0 + sc);
    *(int4*)(sA + (sr + 64) * BK + sc) = *(const int4*)(Ab + (long long)(sr + 64) * HID + k0 + sc);
    *(int4*)(sB + sr * BK + sc)        = *(const int4*)(Bb + (long long)sr * HID + k0 + sc);
    *(int4*)(sB + (sr + 64) * BK + sc) = *(const int4*)(Bb + (long long)(sr + 64) * HID + k0 + sc);
    __syncthreads();
    int rsel = lane & 15;
    int ksel = (lane >> 4) << 4;
    v4i af[4], bf[4];
    for (int i = 0; i < 4; i++) af[i] = *(const v4i*)(sA + (wm + i * 16 + rsel) * BK + ksel);
    for (int j = 0; j < 4; j++) bf[j] = *(const v4i*)(sB + (wn + j * 16 + rsel) * BK + ksel);
    for (int i = 0; i < 4; i++)
      for (int j = 0; j < 4; j++)
        acc[i][j] = __builtin_amdgcn_mfma_i32_16x16x64_i8(af[i], bf[j], acc[i][j], 0, 0, 0);
  }
  float so = scales[1];
  int rowb = (int)m0 + wm + ((lane >> 4) << 2);
  int colb = (int)n0 + wn + (lane & 15);
  for (int i = 0; i < 4; i++) {
    for (int r = 0; r < 4; r++) {
      int token = rowb + i * 16 + r;
      float ds = d2[token] * so;
      const float* xrow = x + (long long)token * DMODEL;
      float* orow = out + (long long)token * DMODEL;
      for (int j = 0; j < 4; j++) {
        int c = colb + j * 16;
        orow[c] = xrow[c] + (float)acc[i][j][r] * ds;
      }
    }
  }
}

extern "C" void kernel_launch(void* const* d_in, const int* in_sizes, int n_in,
                              void* d_out, int out_size, void* d_ws, size_t ws_size,
                              hipStream_t stream) {
  const float* x      = (const float*)d_in[0];
  const float* norm_w = (const float*)d_in[1];
  const float* w_gv   = (const float*)d_in[2];
  const float* w_out  = (const float*)d_in[3];
  float* out = (float*)d_out;

  char* ws = (char*)d_ws;
  size_t off = 0;
  float*   H2    = (float*)(ws + off);   off += (size_t)TOKENS * HID * 4;   // 268 MB
  uint8_t* A2    = (uint8_t*)(ws + off); off += (size_t)TOKENS * HID;       // 67 MB
  uint8_t* Wqgv  = (uint8_t*)(ws + off); off += (size_t)2 * HID * DMODEL;   // 33.5 MB
  uint8_t* Wqout = (uint8_t*)(ws + off); off += (size_t)DMODEL * HID;       // 16.8 MB
  uint8_t* A1    = (uint8_t*)(ws + off); off += (size_t)TOKENS * DMODEL;    // 16.8 MB
  float*   d1    = (float*)(ws + off);   off += (size_t)TOKENS * 4;
  float*   d2    = (float*)(ws + off);   off += (size_t)TOKENS * 4;
  double*  pgv   = (double*)(ws + off);  off += 1024 * 8;
  double*  pout  = (double*)(ws + off);  off += 512 * 8;
  float*   scales = (float*)(ws + off);  off += 16;

  const long long ngv = (long long)2 * HID * DMODEL;   // 33554432
  const long long nout = (long long)DMODEL * HID;      // 16777216

  k_abssum<<<1024, 256, 0, stream>>>(w_gv, ngv / 4, pgv);
  k_abssum<<<512, 256, 0, stream>>>(w_out, nout / 4, pout);
  k_finalize<<<1, 256, 0, stream>>>(pgv, 1024, (double)ngv, pout, 512, (double)nout, scales);
  k_wquant<<<(int)((ngv / 4 + 255) / 256), 256, 0, stream>>>(w_gv, ngv / 4, scales + 0, Wqgv);
  k_wquant<<<(int)((nout / 4 + 255) / 256), 256, 0, stream>>>(w_out, nout / 4, scales + 1, Wqout);
  k_rmsnorm_quant<<<TOKENS, 256, 0, stream>>>(x, norm_w, A1, d1);
  k_gemm1_swiglu<<<dim3(HID / 128, TOKENS / 128), 256, 0, stream>>>(A1, Wqgv, d1, scales, H2);
  k_hquant<<<TOKENS, 256, 0, stream>>>(H2, A2, d2);
  k_gemm2_resid<<<dim3(DMODEL / 128, TOKENS / 128), 256, 0, stream>>>(A2, Wqout, d2, scales, x, out);
}